// Round 4
// baseline (601.991 us; speedup 1.0000x reference)
//
#include <hip/hip_runtime.h>
#include <hip/hip_bf16.h>
#include <math.h>
#include <stdint.h>

#define DIM 2048
#define HID 8192
#define NTOK 8192
#define KCAP 4096

// per-tensor fp8 scales (undone in epilogues)
#define S_W1 64.0f
#define S_H  16.0f
#define S_W2 32.0f

typedef __attribute__((ext_vector_type(4))) float floatx4;
typedef __attribute__((ext_vector_type(4))) int   intx4;
typedef __attribute__((ext_vector_type(8))) int   intx8;

__device__ __forceinline__ unsigned int pk4_fp8(float a, float b, float c, float d) {
    int v = __builtin_amdgcn_cvt_pk_fp8_f32(a, b, 0, false);
    v = __builtin_amdgcn_cvt_pk_fp8_f32(c, d, v, true);
    return (unsigned int)v;
}
__device__ __forceinline__ unsigned char fp8b(float a) {
    return (unsigned char)(__builtin_amdgcn_cvt_pk_fp8_f32(a, 0.0f, 0, false) & 0xff);
}

typedef const __attribute__((address_space(1))) unsigned int* gu32p;
typedef __attribute__((address_space(3))) unsigned int* lu32p;
__device__ __forceinline__ void load16_lds(const void* g, void* l) {
    __builtin_amdgcn_global_load_lds((gu32p)g, (lu32p)l, 16, 0, 0);
}

// ---------------- RMSNorm + router logit + out=x passthrough + fp8 x_norm ----------------
__launch_bounds__(256)
__global__ void rmsnorm_router(const float* __restrict__ x,
                               const float* __restrict__ nw,
                               const float* __restrict__ rw,
                               const float* __restrict__ rb,
                               unsigned char* __restrict__ xq,
                               float* __restrict__ logits,
                               float* __restrict__ out) {
    const int row = blockIdx.x;
    const int t = threadIdx.x;
    const float4* x4 = (const float4*)(x + (size_t)row * DIM);
    float4 a = x4[t];
    float4 b = x4[t + 256];
    float ss = a.x*a.x + a.y*a.y + a.z*a.z + a.w*a.w
             + b.x*b.x + b.y*b.y + b.z*b.z + b.w*b.w;
    for (int off = 32; off > 0; off >>= 1) ss += __shfl_down(ss, off, 64);
    __shared__ float red[4];
    int wave = t >> 6, lane = t & 63;
    if (lane == 0) red[wave] = ss;
    __syncthreads();
    float tot = red[0] + red[1] + red[2] + red[3];
    float rs = rsqrtf(tot / (float)DIM + 1e-6f);

    // out = x passthrough (selected rows get overwritten by GEMM2 epilogue)
    float4* o4 = (float4*)(out + (size_t)row * DIM);
    o4[t] = a;
    o4[t + 256] = b;

    const float4* nw4 = (const float4*)nw;
    const float4* rw4 = (const float4*)rw;
    float4 w0 = nw4[t], w1 = nw4[t + 256];
    float4 r0 = rw4[t], r1 = rw4[t + 256];
    float4 n0, n1;
    n0.x = a.x*rs*w0.x; n0.y = a.y*rs*w0.y; n0.z = a.z*rs*w0.z; n0.w = a.w*rs*w0.w;
    n1.x = b.x*rs*w1.x; n1.y = b.y*rs*w1.y; n1.z = b.z*rs*w1.z; n1.w = b.w*rs*w1.w;
    float dot = n0.x*r0.x + n0.y*r0.y + n0.z*r0.z + n0.w*r0.w
              + n1.x*r1.x + n1.y*r1.y + n1.z*r1.z + n1.w*r1.w;

    unsigned char* xr = xq + (size_t)row * DIM;
    *(unsigned int*)(xr + 4*t)        = pk4_fp8(n0.x, n0.y, n0.z, n0.w);
    *(unsigned int*)(xr + 4*t + 1024) = pk4_fp8(n1.x, n1.y, n1.z, n1.w);

    for (int off = 32; off > 0; off >>= 1) dot += __shfl_down(dot, off, 64);
    __syncthreads();                 // protect red reuse
    if (lane == 0) red[wave] = dot;
    __syncthreads();
    if (t == 0) logits[row] = red[0] + red[1] + red[2] + red[3] + rb[0];
}

// ---------------- fused fp32 -> fp8 transpose of both weights ----------------
// z==0: w1 [DIM][HID] -> w1q [HID][DIM] * S_W1 ;  z==1: w2 [HID][DIM] -> w2q [DIM][HID] * S_W2
__launch_bounds__(256)
__global__ void transpose_fp8(const float* __restrict__ w1, unsigned char* __restrict__ w1q,
                              const float* __restrict__ w2, unsigned char* __restrict__ w2q) {
    const float* src; unsigned char* dst; int R, C, c0, r0; float scale;
    if (blockIdx.z == 0) { src = w1; dst = w1q; R = DIM; C = HID; scale = S_W1;
                           c0 = blockIdx.x * 32; r0 = blockIdx.y * 32; }
    else                 { src = w2; dst = w2q; R = HID; C = DIM; scale = S_W2;
                           c0 = blockIdx.y * 32; r0 = blockIdx.x * 32; }
    __shared__ float tile[32][33];
    const int t = threadIdx.x;
    const int tx = t & 31, ty = t >> 5;               // 32 x 8
    #pragma unroll
    for (int i = 0; i < 32; i += 8)
        tile[ty + i][tx] = src[(size_t)(r0 + ty + i) * C + c0 + tx];
    __syncthreads();
    // packed 4-byte stores: thread -> out row oc = t>>3, cols ob..ob+3
    const int oc = t >> 3, ob = (t & 7) * 4;
    unsigned int pk = pk4_fp8(tile[ob][oc] * scale, tile[ob + 1][oc] * scale,
                              tile[ob + 2][oc] * scale, tile[ob + 3][oc] * scale);
    *(unsigned int*)(dst + (size_t)(c0 + oc) * R + r0 + ob) = pk;
}

// ---------------- exact rank counting (jax top_k tie-break: lower index wins) ----------------
// partial ranks per 1024-chunk, no atomics (pure overwrite -> no memset needed)
#define JCHUNK 1024
__launch_bounds__(256)
__global__ void rank_partial(const float* __restrict__ logits, int* __restrict__ cnt8) {
    __shared__ float ls[JCHUNK];
    const int j0 = blockIdx.y * JCHUNK;
    for (int j = threadIdx.x; j < JCHUNK; j += 256) ls[j] = logits[j0 + j];
    __syncthreads();
    const int i = blockIdx.x * 256 + threadIdx.x;
    const float my = logits[i];
    int c = 0;
    #pragma unroll 8
    for (int j = 0; j < JCHUNK; j++) {
        float v = ls[j];
        c += (v > my) || (v == my && (j0 + j) < i);
    }
    cnt8[blockIdx.y * NTOK + i] = c;
}

// rank < KCAP  =>  slot = rank (strict total order makes ranks bijective onto 0..KCAP-1)
__launch_bounds__(256)
__global__ void rank_finalize(const int* __restrict__ cnt8, int* __restrict__ sel_idx) {
    const int i = blockIdx.x * 256 + threadIdx.x;
    int r = 0;
    #pragma unroll
    for (int c = 0; c < 8; c++) r += cnt8[c * NTOK + i];
    if (r < KCAP) sel_idx[r] = i;
}

// ---------------- MX-fp8 MFMA GEMM: C[M][N] = A[M][K] * Bt[N][K]^T ----------------
// 128x128 tile, BK=128 bytes, 4 waves x (4x4) 16x16x128 f8f6f4 MFMA (scale=1.0).
// K-MAJOR LDS: As[chunk c][row] (addr = c*2048 + row*16). Read addresses are
// loop-invariant (one base + immediate offsets); fragment halves load directly
// into the intx8 halves (no assembly movs). Staging = per-lane global gather,
// LDS dest lane-ordered (required by global_load_lds).
// MODE 1: A rows gathered via sel_idx; epilogue acc/S + b1 -> gelu -> fp8*S_H into h.
// MODE 2: A = h (slot-major); epilogue out[token] = x[token] + (acc/S + b2)*gamma.
template<int MODE>
__launch_bounds__(256)
__global__ void gemm_mx(const unsigned char* __restrict__ A,
                        const unsigned char* __restrict__ Bt,
                        const float* __restrict__ bias,
                        const int* __restrict__ sel_idx,
                        const float* __restrict__ x,
                        const float* __restrict__ gamma,
                        void* __restrict__ Cout,
                        int N, int K, float inv_scale) {
    __shared__ __align__(16) unsigned char As[8 * 2048];
    __shared__ __align__(16) unsigned char Bs[8 * 2048];
    const int t = threadIdx.x;
    const int row_a0 = blockIdx.x * 128;
    const int row_b0 = blockIdx.y * 128;

    const int wave = t >> 6, lane = t & 63;
    const int wm = (wave & 1) * 64, wn = (wave >> 1) * 64;
    const int quad = lane >> 4, l16 = lane & 15;

    // staging: 32 instructions/block/iter; wave w issues j=0..7, n = w*8+j
    // n: mat = n>>4 (0=A,1=B), chunk c = (n>>1)&7, row-half h = n&1; row = h*64+lane
    const unsigned char* gp[8];
    unsigned char* lp[8];
    #pragma unroll
    for (int j = 0; j < 8; j++) {
        const int n = wave * 8 + j;
        const int mat = n >> 4, c = (n >> 1) & 7, h = n & 1;
        const int r = h * 64 + lane;
        if (mat == 0) {
            long arow = (MODE == 1) ? (long)sel_idx[row_a0 + r] : (long)(row_a0 + r);
            gp[j] = A + arow * (long)K + c * 16;
            lp[j] = As + c * 2048 + h * 1024 + lane * 16;
        } else {
            gp[j] = Bt + (size_t)(row_b0 + r) * K + c * 16;
            lp[j] = Bs + c * 2048 + h * 1024 + lane * 16;
        }
    }

    // loop-invariant read bases: lane covers k-chunks 2q (base) and 2q+1 (+2048);
    // fragment i at +i*256
    const unsigned char* baseA = As + quad * 4096 + (wm + l16) * 16;
    const unsigned char* baseB = Bs + quad * 4096 + (wn + l16) * 16;

    floatx4 acc[4][4] = {};

    for (int k0 = 0; k0 < K; k0 += 128) {
        __syncthreads();                             // previous compute done before overwrite
        #pragma unroll
        for (int j = 0; j < 8; j++) { load16_lds(gp[j], lp[j]); gp[j] += 128; }
        __builtin_amdgcn_s_waitcnt(0);               // drain vmcnt before barrier
        __syncthreads();

        intx8 af[4], bf[4];
        intx4* afh = (intx4*)af;
        intx4* bfh = (intx4*)bf;
        #pragma unroll
        for (int i = 0; i < 4; i++) {
            afh[2 * i]     = *(const intx4*)(baseA + i * 256);          // chunk 2q
            afh[2 * i + 1] = *(const intx4*)(baseA + i * 256 + 2048);   // chunk 2q+1
            bfh[2 * i]     = *(const intx4*)(baseB + i * 256);
            bfh[2 * i + 1] = *(const intx4*)(baseB + i * 256 + 2048);
        }
        #pragma unroll
        for (int i = 0; i < 4; i++)
            #pragma unroll
            for (int j = 0; j < 4; j++)
                acc[i][j] = __builtin_amdgcn_mfma_scale_f32_16x16x128_f8f6f4(
                    af[i], bf[j], acc[i][j], 0, 0,    // cbsz=fp8, blgp=fp8
                    0, 0x7F7F7F7F,                    // scale_a = 1.0
                    0, 0x7F7F7F7F);                   // scale_b = 1.0
    }

    // C/D layout: col = lane&15 (within 16-tile), row = quad*4 + r
    if (MODE == 1) {
        unsigned char* C = (unsigned char*)Cout;
        #pragma unroll
        for (int i = 0; i < 4; i++) {
            #pragma unroll
            for (int j = 0; j < 4; j++) {
                int cc = row_b0 + wn + j * 16 + l16;
                float bv = bias[cc];
                #pragma unroll
                for (int r = 0; r < 4; r++) {
                    int rr = row_a0 + wm + i * 16 + quad * 4 + r;
                    float v = acc[i][j][r] * inv_scale + bv;
                    v = 0.5f * v * (1.0f + erff(v * 0.70710678118654752f));
                    C[(size_t)rr * N + cc] = fp8b(v * S_H);
                }
            }
        }
    } else {
        float* O = (float*)Cout;
        #pragma unroll
        for (int i = 0; i < 4; i++) {
            #pragma unroll
            for (int r = 0; r < 4; r++) {
                int slot = row_a0 + wm + i * 16 + quad * 4 + r;
                long token = sel_idx[slot];
                const float* xrow = x + token * (long)DIM;
                float* orow = O + token * (long)DIM;
                #pragma unroll
                for (int j = 0; j < 4; j++) {
                    int cc = row_b0 + wn + j * 16 + l16;
                    float v = acc[i][j][r] * inv_scale + bias[cc];
                    orow[cc] = xrow[cc] + v * gamma[cc];
                }
            }
        }
    }
}

extern "C" void kernel_launch(void* const* d_in, const int* in_sizes, int n_in,
                              void* d_out, int out_size, void* d_ws, size_t ws_size,
                              hipStream_t stream) {
    const float* x     = (const float*)d_in[0];
    const float* nw    = (const float*)d_in[1];
    const float* rw    = (const float*)d_in[2];
    const float* rb    = (const float*)d_in[3];
    const float* w1    = (const float*)d_in[4];
    const float* b1    = (const float*)d_in[5];
    const float* w2    = (const float*)d_in[6];
    const float* b2    = (const float*)d_in[7];
    const float* gamma = (const float*)d_in[8];
    float* out = (float*)d_out;

    char* ws = (char*)d_ws;
    size_t off = 0;
    auto alloc = [&](size_t bytes) -> void* {
        void* p = ws + off;
        off = (off + bytes + 255) & ~(size_t)255;
        return p;
    };
    unsigned char* xq  = (unsigned char*)alloc((size_t)NTOK * DIM);   // 16 MB fp8 x_norm
    unsigned char* w1q = (unsigned char*)alloc((size_t)HID * DIM);    // 16 MB fp8 w1^T [HID][DIM]
    unsigned char* w2q = (unsigned char*)alloc((size_t)DIM * HID);    // 16 MB fp8 w2^T [DIM][HID]
    unsigned char* h   = (unsigned char*)alloc((size_t)KCAP * HID);   // 32 MB fp8 hidden
    float* logits      = (float*)alloc((size_t)NTOK * 4);
    int* cnt8          = (int*)alloc((size_t)8 * NTOK * 4);
    int* sel_idx       = (int*)alloc((size_t)KCAP * 4);

    rmsnorm_router<<<NTOK, 256, 0, stream>>>(x, nw, rw, rb, xq, logits, out);
    transpose_fp8<<<dim3(HID / 32, DIM / 32, 2), 256, 0, stream>>>(w1, w1q, w2, w2q);
    rank_partial<<<dim3(NTOK / 256, NTOK / JCHUNK), 256, 0, stream>>>(logits, cnt8);
    rank_finalize<<<NTOK / 256, 256, 0, stream>>>(cnt8, sel_idx);
    gemm_mx<1><<<dim3(KCAP / 128, HID / 128), 256, 0, stream>>>(
        xq, w1q, b1, sel_idx, nullptr, nullptr, (void*)h, HID, DIM, 1.0f / S_W1);
    gemm_mx<2><<<dim3(KCAP / 128, DIM / 128), 256, 0, stream>>>(
        h, w2q, b2, sel_idx, x, gamma, (void*)out, DIM, HID, 1.0f / (S_H * S_W2));
}